// Round 3
// baseline (619.794 us; speedup 1.0000x reference)
//
#include <hip/hip_runtime.h>
#include <hip/hip_bf16.h>
#include <stdint.h>

typedef __attribute__((ext_vector_type(4))) float f32x4;
typedef __attribute__((ext_vector_type(8))) short bf16x8;
typedef __attribute__((ext_vector_type(8))) unsigned short u16x8;

#define LEN_Q 2048
#define LEN_IN 21760

static __device__ __forceinline__ unsigned short f2bf(float f) {
  unsigned int u = __float_as_uint(f);
  u += 0x7fffu + ((u >> 16) & 1u);
  return (unsigned short)(u >> 16);
}
static __device__ __forceinline__ float bf2f(unsigned int us) {
  return __uint_as_float(us << 16);
}

// ---------------------------------------------------------------------------
// Fused prep: weight transposes WT[n][k]=bf16(W[k][n]) + b_oa concat.
// ---------------------------------------------------------------------------
__global__ __launch_bounds__(256) void prep_k(
    const float* __restrict__ Wv, const float* __restrict__ Wo,
    const float* __restrict__ Wa, const float* __restrict__ Wu,
    const float* __restrict__ W1, const float* __restrict__ W2,
    const float* __restrict__ boff, const float* __restrict__ batt,
    unsigned short* __restrict__ WTv, unsigned short* __restrict__ WToa,
    unsigned short* __restrict__ WTu, unsigned short* __restrict__ WT1,
    unsigned short* __restrict__ WT2, float* __restrict__ b_oa) {
  int i = blockIdx.x * 256 + threadIdx.x;
  if (i < 65536) { int n = i >> 8, k = i & 255; WTv[i] = f2bf(Wv[k * 256 + n]); return; }
  i -= 65536;
  if (i < 65536) { int n = i >> 8, k = i & 255; WToa[i] = f2bf(Wo[k * 256 + n]); return; }
  i -= 65536;
  if (i < 32768) { int n = i >> 8, k = i & 255; WToa[65536 + i] = f2bf(Wa[k * 128 + n]); return; }
  i -= 32768;
  if (i < 65536) { int n = i >> 8, k = i & 255; WTu[i] = f2bf(Wu[k * 256 + n]); return; }
  i -= 65536;
  if (i < 262144) { int n = i >> 8, k = i & 255; WT1[i] = f2bf(W1[k * 1024 + n]); return; }
  i -= 262144;
  if (i < 262144) { int n = i >> 10, k = i & 1023; WT2[i] = f2bf(W2[k * 256 + n]); return; }
  i -= 262144;
  if (i < 256) { b_oa[i] = boff[i]; return; }
  i -= 256;
  if (i < 128) { b_oa[256 + i] = batt[i]; }
}

// ---------------------------------------------------------------------------
// Value-proj GEMM, persistent. M=174080, N=256, K=256.
// 512 thr = 8 waves. Each wave: 32 output cols, FULL B panel (32x256 bf16) in
// 64 VGPRs loaded once. A = bf16(mem+posm) staged per 64-row tile into
// XOR-swizzled LDS (conflict-free ds_read_b128), double-buffered, 1 barrier
// per tile; next tile's f32 loads issued before compute (latency hidden).
// ---------------------------------------------------------------------------
__global__ __launch_bounds__(512) void gemmv_k(
    const float* __restrict__ A1, const float* __restrict__ A2,
    const unsigned short* __restrict__ BT, const float* __restrict__ bias,
    unsigned short* __restrict__ Ob) {
  __shared__ unsigned short As[2][64][256];   // 64 KiB, XOR-swizzled rows
  const int tid = threadIdx.x;
  const int w = tid >> 6, lane = tid & 63;
  const int lr = lane & 15, lk8 = (lane >> 4) << 3;

  // B panel -> regs (L2-resident: all blocks read same 128KB)
  bf16x8 breg[2][8];
#pragma unroll
  for (int g = 0; g < 2; ++g) {
    const unsigned short* bp = BT + (size_t)(w * 32 + g * 16 + lr) * 256 + lk8;
#pragma unroll
    for (int c = 0; c < 8; ++c) breg[g][c] = *(const bf16x8*)(bp + c * 32);
  }
  float bv0[2];
#pragma unroll
  for (int g = 0; g < 2; ++g) bv0[g] = bias[w * 32 + g * 16 + lr];

  const int b = blockIdx.x;
  const int nt = 10 + (b < 160 ? 1 : 0);
  int t = b * 10 + (b < 160 ? b : 160);

  const int row = tid >> 3;            // 0..63
  const int c0 = (tid & 7) << 5;       // col chunk of 32
  char* const lbase0 = (char*)&As[0][0][0] + (row << 9);
  char* const lbase1 = (char*)&As[1][0][0] + (row << 9);

  f32x4 a1[8], a2[8];
  auto issueA = [&](int tt) {
    const float* p1 = A1 + (((size_t)(tt * 64 + row)) << 8) + c0;
    const float* p2 = A2 + (((size_t)(tt * 64 + row)) << 8) + c0;
#pragma unroll
    for (int j = 0; j < 8; ++j) {
      a1[j] = *(const f32x4*)(p1 + j * 4);
      a2[j] = *(const f32x4*)(p2 + j * 4);
    }
  };
  auto writeA = [&](int buf) {
    char* base = buf ? lbase1 : lbase0;
#pragma unroll
    for (int j = 0; j < 4; ++j) {
      u16x8 tv;
#pragma unroll
      for (int q = 0; q < 4; ++q) {
        tv[q] = f2bf(a1[2 * j][q] + a2[2 * j][q]);
        tv[4 + q] = f2bf(a1[2 * j + 1][q] + a2[2 * j + 1][q]);
      }
      int off = ((c0 + j * 8) << 1) ^ ((row & 7) << 4);
      *(u16x8*)(base + off) = tv;
    }
  };

  issueA(t);
  writeA(0);
  __syncthreads();

  int p = 0;
  for (int i = 0; i < nt; ++i, ++t) {
    if (i + 1 < nt) issueA(t + 1);
    f32x4 acc[4][2];
#pragma unroll
    for (int m = 0; m < 4; ++m)
#pragma unroll
      for (int g = 0; g < 2; ++g) acc[m][g] = (f32x4){0.f, 0.f, 0.f, 0.f};
    const char* rb = (const char*)&As[p][0][0];
#pragma unroll
    for (int c = 0; c < 8; ++c) {
      bf16x8 af[4];
#pragma unroll
      for (int m = 0; m < 4; ++m) {
        const int r_ = m * 16 + lr;
        int off = (r_ << 9) + ((c * 32 + lk8) << 1);
        off ^= (r_ & 7) << 4;
        af[m] = *(const bf16x8*)(rb + off);
      }
#pragma unroll
      for (int g = 0; g < 2; ++g)
#pragma unroll
        for (int m = 0; m < 4; ++m)
          acc[m][g] = __builtin_amdgcn_mfma_f32_16x16x32_bf16(af[m], breg[g][c], acc[m][g], 0, 0, 0);
    }
    // store tile t (overlaps the vmcnt wait of issueA)
#pragma unroll
    for (int m = 0; m < 4; ++m) {
      const int rg = t * 64 + m * 16 + ((lane >> 4) << 2);
#pragma unroll
      for (int g = 0; g < 2; ++g) {
        const int cg = w * 32 + g * 16 + lr;
#pragma unroll
        for (int r = 0; r < 4; ++r)
          Ob[((size_t)(rg + r) << 8) + cg] = f2bf(acc[m][g][r] + bv0[g]);
      }
    }
    if (i + 1 < nt) writeA(p ^ 1);
    __syncthreads();
    p ^= 1;
  }
}

// ---------------------------------------------------------------------------
// Query-side GEMM (M=16384 rows, one 64-row tile per block).
// B panel held in regs per wave (NF*K/4 VGPRs); A staged full-K into swizzled
// LDS in 256-col super-chunks. FUSEA: A=bf16(A1+A2) f32 inputs.
// EPI: 1 = f32 store, 2 = relu+bf16 store.
// ---------------------------------------------------------------------------
template <int FUSEA, int NF, int KK, int EPI>
__global__ __launch_bounds__(512) void gemmq_k(
    const float* __restrict__ A1, const float* __restrict__ A2,
    const unsigned short* __restrict__ Abf,
    const unsigned short* __restrict__ BT, const float* __restrict__ bias,
    float* __restrict__ Of, unsigned short* __restrict__ Ob, int N) {
  constexpr int NSUP = KK / 256;
  __shared__ unsigned short As[64][256];
  const int tid = threadIdx.x;
  const int w = tid >> 6, lane = tid & 63;
  const int lr = lane & 15, lk8 = (lane >> 4) << 3;
  const int bm0 = blockIdx.x * 64, bn0 = blockIdx.y * (NF * 128);

  bf16x8 breg[NF][KK / 32];
#pragma unroll
  for (int g = 0; g < NF; ++g) {
    const unsigned short* bp = BT + (size_t)(bn0 + w * 16 * NF + g * 16 + lr) * KK + lk8;
#pragma unroll
    for (int c = 0; c < KK / 32; ++c) breg[g][c] = *(const bf16x8*)(bp + c * 32);
  }

  f32x4 acc[4][NF];
#pragma unroll
  for (int m = 0; m < 4; ++m)
#pragma unroll
    for (int g = 0; g < NF; ++g) acc[m][g] = (f32x4){0.f, 0.f, 0.f, 0.f};

  const int row = tid >> 3, c0 = (tid & 7) << 5;
  char* const wbase = (char*)&As[0][0] + (row << 9);

#pragma unroll
  for (int s = 0; s < NSUP; ++s) {
    if (s) __syncthreads();
    if (FUSEA) {
      const float* p1 = A1 + (size_t)(bm0 + row) * KK + s * 256 + c0;
      const float* p2 = A2 + (size_t)(bm0 + row) * KK + s * 256 + c0;
#pragma unroll
      for (int j = 0; j < 4; ++j) {
        f32x4 u0 = *(const f32x4*)(p1 + j * 8);
        f32x4 u1 = *(const f32x4*)(p1 + j * 8 + 4);
        f32x4 v0 = *(const f32x4*)(p2 + j * 8);
        f32x4 v1 = *(const f32x4*)(p2 + j * 8 + 4);
        u16x8 tv;
#pragma unroll
        for (int q = 0; q < 4; ++q) {
          tv[q] = f2bf(u0[q] + v0[q]);
          tv[4 + q] = f2bf(u1[q] + v1[q]);
        }
        int off = ((c0 + j * 8) << 1) ^ ((row & 7) << 4);
        *(u16x8*)(wbase + off) = tv;
      }
    } else {
      const unsigned short* pa = Abf + (size_t)(bm0 + row) * KK + s * 256 + c0;
#pragma unroll
      for (int j = 0; j < 4; ++j) {
        u16x8 tv = *(const u16x8*)(pa + j * 8);
        int off = ((c0 + j * 8) << 1) ^ ((row & 7) << 4);
        *(u16x8*)(wbase + off) = tv;
      }
    }
    __syncthreads();
#pragma unroll
    for (int c = 0; c < 8; ++c) {
      bf16x8 af[4];
#pragma unroll
      for (int m = 0; m < 4; ++m) {
        const int r_ = m * 16 + lr;
        int off = (r_ << 9) + ((c * 32 + lk8) << 1);
        off ^= (r_ & 7) << 4;
        af[m] = *(const bf16x8*)((const char*)&As[0][0] + off);
      }
#pragma unroll
      for (int g = 0; g < NF; ++g)
#pragma unroll
        for (int m = 0; m < 4; ++m)
          acc[m][g] = __builtin_amdgcn_mfma_f32_16x16x32_bf16(af[m], breg[g][s * 8 + c], acc[m][g], 0, 0, 0);
    }
  }

#pragma unroll
  for (int m = 0; m < 4; ++m) {
    const int rg = bm0 + m * 16 + ((lane >> 4) << 2);
#pragma unroll
    for (int g = 0; g < NF; ++g) {
      const int cg = bn0 + w * 16 * NF + g * 16 + lr;
      const float bv = bias[cg];
#pragma unroll
      for (int r = 0; r < 4; ++r) {
        float val = acc[m][g][r] + bv;
        if (EPI == 2) val = fmaxf(val, 0.f);
        size_t o = (size_t)(rg + r) * N + cg;
        if (EPI == 1) Of[o] = val;
        else Ob[o] = f2bf(val);
      }
    }
  }
}

// ---------------------------------------------------------------------------
// Deformable sampling. Block = one (n,q) row, 128 threads = 8 heads x 16
// channel-pairs. Softmax over 16 per head; bilinear gather from v bf16.
// ---------------------------------------------------------------------------
__global__ __launch_bounds__(128) void msda_k(
    const float* __restrict__ offattn, const float* __restrict__ refp,
    const unsigned short* __restrict__ v, unsigned short* __restrict__ out) {
  const int row = blockIdx.x;
  const int n = row >> 11;
  const int t = threadIdx.x;
  const int h = t >> 4, c2 = t & 15;
  const float* oa = offattn + (size_t)row * 384;
  const float* at = oa + 256 + h * 16;
  float lg[16];
  float mx = -1e30f;
#pragma unroll
  for (int i = 0; i < 16; ++i) { lg[i] = at[i]; mx = fmaxf(mx, lg[i]); }
  float den = 0.f;
#pragma unroll
  for (int i = 0; i < 16; ++i) { lg[i] = __expf(lg[i] - mx); den += lg[i]; }
  const float rden = 1.f / den;

  const int HL[4] = {128, 64, 32, 16};
  const int S0[4] = {0, 16384, 20480, 21504};
  float acc0 = 0.f, acc1 = 0.f;
  const unsigned short* vb = v + (size_t)n * LEN_IN * 256 + h * 32 + (c2 << 1);
#pragma unroll
  for (int l = 0; l < 4; ++l) {
    const int W = HL[l], H = HL[l];
    const float Wf = (float)W;
    const int s0 = S0[l];
    const float rx = refp[(size_t)row * 8 + l * 2 + 0];
    const float ry = refp[(size_t)row * 8 + l * 2 + 1];
#pragma unroll
    for (int p = 0; p < 4; ++p) {
      const float ox = oa[h * 32 + l * 8 + p * 2 + 0];
      const float oy = oa[h * 32 + l * 8 + p * 2 + 1];
      float x = rx * Wf + ox - 0.5f;
      float y = ry * Wf + oy - 0.5f;
      float x0f = floorf(x), y0f = floorf(y);
      float wx = x - x0f, wy = y - y0f;
      int x0 = (int)x0f, y0 = (int)y0f;
      float wgt = lg[l * 4 + p] * rden;
#pragma unroll
      for (int cy = 0; cy < 2; ++cy) {
        int yi = y0 + cy;
        float wyf = cy ? wy : (1.f - wy);
        bool vy = (yi >= 0) & (yi < H);
        int yc = min(max(yi, 0), H - 1);
#pragma unroll
        for (int cx = 0; cx < 2; ++cx) {
          int xi = x0 + cx;
          float wxf = cx ? wx : (1.f - wx);
          bool vx = (xi >= 0) & (xi < W);
          int xc = min(max(xi, 0), W - 1);
          unsigned int pv = *(const unsigned int*)(vb + (size_t)(s0 + yc * W + xc) * 256);
          float wv = (vx & vy) ? (wgt * wyf * wxf) : 0.f;
          acc0 += wv * bf2f(pv & 0xffffu);
          acc1 += wv * bf2f(pv >> 16);
        }
      }
    }
  }
  unsigned int pr = ((unsigned int)f2bf(acc1) << 16) | (unsigned int)f2bf(acc0);
  *(unsigned int*)(out + (size_t)row * 256 + h * 32 + (c2 << 1)) = pr;
}

// ---------------------------------------------------------------------------
// Residual + LayerNorm over 256 cols. One block per row, shuffle reduce.
// ---------------------------------------------------------------------------
__global__ __launch_bounds__(256) void ln_k(
    const float* __restrict__ resid, const float* __restrict__ y,
    const float* __restrict__ g, const float* __restrict__ b,
    float* __restrict__ Of, unsigned short* __restrict__ Ob) {
  const int row = blockIdx.x, t = threadIdx.x;
  const size_t idx = (size_t)row * 256 + t;
  const float v = resid[idx] + y[idx];
  float s1 = v, s2 = v * v;
#pragma unroll
  for (int d = 32; d > 0; d >>= 1) {
    s1 += __shfl_xor(s1, d, 64);
    s2 += __shfl_xor(s2, d, 64);
  }
  __shared__ float p1[4], p2[4];
  const int w = t >> 6;
  if ((t & 63) == 0) { p1[w] = s1; p2[w] = s2; }
  __syncthreads();
  const float mu = (p1[0] + p1[1] + p1[2] + p1[3]) * (1.f / 256.f);
  const float m2 = (p2[0] + p2[1] + p2[2] + p2[3]) * (1.f / 256.f);
  const float var = m2 - mu * mu;
  const float o = (v - mu) * rsqrtf(var + 1e-5f) * g[t] + b[t];
  Of[idx] = o;
  if (Ob) Ob[idx] = f2bf(o);
}

// ---------------------------------------------------------------------------
extern "C" void kernel_launch(void* const* d_in, const int* in_sizes, int n_in,
                              void* d_out, int out_size, void* d_ws, size_t ws_size,
                              hipStream_t stream) {
  const float* src   = (const float*)d_in[0];
  const float* pos   = (const float*)d_in[1];
  const float* mem   = (const float*)d_in[2];
  const float* posm  = (const float*)d_in[3];
  const float* refp  = (const float*)d_in[4];
  const float* W_off = (const float*)d_in[7];
  const float* b_off = (const float*)d_in[8];
  const float* W_at  = (const float*)d_in[9];
  const float* b_at  = (const float*)d_in[10];
  const float* W_val = (const float*)d_in[11];
  const float* b_val = (const float*)d_in[12];
  const float* W_out = (const float*)d_in[13];
  const float* b_out = (const float*)d_in[14];
  const float* g1    = (const float*)d_in[15];
  const float* be1   = (const float*)d_in[16];
  const float* W_ff1 = (const float*)d_in[17];
  const float* b_ff1 = (const float*)d_in[18];
  const float* W_ff2 = (const float*)d_in[19];
  const float* b_ff2 = (const float*)d_in[20];
  const float* g2    = (const float*)d_in[21];
  const float* be2   = (const float*)d_in[22];
  float* out = (float*)d_out;

  const int R = 8 * LEN_Q;          // 16384 query rows
  const int MV = 8 * LEN_IN;        // 174080 value rows

  char* ws = (char*)d_ws;
  size_t woff = 0;
  auto alloc = [&](size_t bytes) {
    char* p = ws + woff;
    woff += (bytes + 255) & ~(size_t)255;
    return p;
  };
  unsigned short* WT_val = (unsigned short*)alloc(256 * 256 * 2);
  unsigned short* WT_oa  = (unsigned short*)alloc(384 * 256 * 2);
  float* b_oa            = (float*)alloc(384 * 4);
  unsigned short* WT_out = (unsigned short*)alloc(256 * 256 * 2);
  unsigned short* WT_f1  = (unsigned short*)alloc(1024 * 256 * 2);
  unsigned short* WT_f2  = (unsigned short*)alloc(256 * 1024 * 2);
  unsigned short* vb     = (unsigned short*)alloc((size_t)MV * 256 * 2);
  float* offattn         = (float*)alloc((size_t)R * 384 * 4);
  unsigned short* attno  = (unsigned short*)alloc((size_t)R * 256 * 2);
  float* tmp             = (float*)alloc((size_t)R * 256 * 4);
  float* xf              = (float*)alloc((size_t)R * 256 * 4);
  unsigned short* xb     = (unsigned short*)alloc((size_t)R * 256 * 2);
  unsigned short* hb     = (unsigned short*)alloc((size_t)R * 1024 * 2);

  // weight prep
  prep_k<<<2946, 256, 0, stream>>>(W_val, W_off, W_at, W_out, W_ff1, W_ff2,
                                   b_off, b_at, WT_val, WT_oa, WT_out, WT_f1,
                                   WT_f2, b_oa);

  // value proj: v = (mem+posm)@W_val + b_val -> bf16 [174080,256]
  gemmv_k<<<256, 512, 0, stream>>>(mem, posm, WT_val, b_val, vb);

  // offsets + attn logits (fused q=src+pos): [16384,384] f32
  gemmq_k<1, 3, 256, 1><<<dim3(R / 64, 1), 512, 0, stream>>>(
      src, pos, nullptr, WT_oa, b_oa, offattn, nullptr, 384);

  // deformable sampling -> attno bf16 [16384,256]
  msda_k<<<R, 128, 0, stream>>>(offattn, refp, vb, attno);

  // output proj -> tmp f32
  gemmq_k<0, 2, 256, 1><<<dim3(R / 64, 1), 512, 0, stream>>>(
      nullptr, nullptr, attno, WT_out, b_out, tmp, nullptr, 256);
  ln_k<<<R, 256, 0, stream>>>(src, tmp, g1, be1, xf, xb);

  // FFN
  gemmq_k<0, 4, 256, 2><<<dim3(R / 64, 2), 512, 0, stream>>>(
      nullptr, nullptr, xb, WT_f1, b_ff1, nullptr, hb, 1024);
  gemmq_k<0, 1, 1024, 1><<<dim3(R / 64, 2), 512, 0, stream>>>(
      nullptr, nullptr, hb, WT_f2, b_ff2, tmp, nullptr, 256);
  ln_k<<<R, 256, 0, stream>>>(xf, tmp, g2, be2, out, nullptr);
}